// Round 9
// baseline (63.633 us; speedup 1.0000x reference)
//
#include <hip/hip_runtime.h>
#include <hip/hip_bf16.h>

#define NN 1024   // batch
#define ND 512    // embed dim (K)
#define NM 512    // prototypes

typedef __attribute__((ext_vector_type(8))) short short8;   // 8 bf16 = 4 VGPR (MFMA A/B frag)
typedef __attribute__((ext_vector_type(4))) float f32x4;    // MFMA C/D frag

__device__ __forceinline__ ushort f2bf(float f) {           // f32 -> bf16 RNE
    union { float f; unsigned u; } v; v.f = f;
    unsigned r = v.u + 0x7FFFu + ((v.u >> 16) & 1u);
    return (ushort)(r >> 16);
}

// ---------------------------------------------------------------------------
// out[n,m] = -0.5*sqrt(xx[n] + pp[m] - 2*dot(x_n, p_m))
// 32n x 32m tile, 512 blocks (2/CU for cross-block stall hiding), 256 threads
// (4 waves, one 16x16 frag each), BK=64, mfma_f32_16x16x32_bf16.
// P transposed in-flight (coalesced along m); norms fused into staging.
// Step order: stage -> barrier -> prefetch(next) -> MFMA. The prefetch issues
// AFTER the barrier so the compiler's vmcnt(0)-before-s_barrier does NOT
// drain next-step loads at this step's barrier; the wait lands at the
// register use one MFMA-phase later, and the co-resident second block
// covers the remaining latency.
// Grid (n-tiles=32, m-tiles=16): XCD = linear%8 = x%8 -> each XCD reuses
// 4 X-slabs + full P (~1.25MB working set < 4MB L2).
// ---------------------------------------------------------------------------
__global__ __launch_bounds__(256, 2) void fused_kernel(const float* __restrict__ X,
                                                       const float* __restrict__ P,
                                                       float* __restrict__ out) {
    // 72-elem rows (144B): 16B-aligned, row-unit rotation (r*9 mod 8) balances
    // banks for both b128 writes and b128 reads (only 2-way aliasing = free).
    __shared__ ushort As[2][32][72];
    __shared__ ushort Bs[2][32][72];
    __shared__ float  xx_s[32];
    __shared__ float  pp_part[8][32];

    const int t  = threadIdx.x;
    const int n0 = blockIdx.x * 32;   // grid.x = n-tiles (XCD locality)
    const int m0 = blockIdx.y * 32;   // grid.y = m-tiles

    // X staging: row sr (0..31), k-octet sk (0..7) -> two float4 per step
    const int sr = t >> 3;
    const int sk = t & 7;
    const float* ax = X + (n0 + sr) * ND + sk * 8;

    // P staging: m-column pm (0..31), k-octet pk (0..7) -> 8 strided f32 per step
    const int pm = t & 31;
    const int pk = t >> 5;
    const float* bp = P + (pk * 8) * NM + m0 + pm;

    const int lane = t & 63;
    const int wid  = t >> 6;          // 0..3
    const int wn   = wid >> 1;        // 0..1  (16n quadrant)
    const int wm   = wid & 1;         // 0..1  (16m quadrant)
    const int fr = lane & 15, fq = lane >> 4;

    float xacc = 0.f, pacc = 0.f;
    f32x4 acc = {0.f, 0.f, 0.f, 0.f};

    float4 a0[2], a1[2];
    float  b[2][8];

    // prologue loads (step 0)
    a0[0] = *(const float4*)ax;
    a1[0] = *(const float4*)(ax + 4);
    #pragma unroll
    for (int j = 0; j < 8; ++j) b[0][j] = bp[j * NM];

    #pragma unroll
    for (int step = 0; step < 8; ++step) {
        const int cur = step & 1, nxt = cur ^ 1;

        // ---- stage X: fold norm (f32), convert, one b128 write
        {
            float4 v0 = a0[cur], v1 = a1[cur];
            xacc = fmaf(v0.x, v0.x, xacc); xacc = fmaf(v0.y, v0.y, xacc);
            xacc = fmaf(v0.z, v0.z, xacc); xacc = fmaf(v0.w, v0.w, xacc);
            xacc = fmaf(v1.x, v1.x, xacc); xacc = fmaf(v1.y, v1.y, xacc);
            xacc = fmaf(v1.z, v1.z, xacc); xacc = fmaf(v1.w, v1.w, xacc);
            unsigned w0 = (unsigned)f2bf(v0.x) | ((unsigned)f2bf(v0.y) << 16);
            unsigned w1 = (unsigned)f2bf(v0.z) | ((unsigned)f2bf(v0.w) << 16);
            unsigned w2 = (unsigned)f2bf(v1.x) | ((unsigned)f2bf(v1.y) << 16);
            unsigned w3 = (unsigned)f2bf(v1.z) | ((unsigned)f2bf(v1.w) << 16);
            *(uint4*)&As[cur][sr][sk * 8] = make_uint4(w0, w1, w2, w3);
        }

        // ---- stage P: fold norm (f32), pack 8 k-consecutive bf16, b128 write
        {
            unsigned w[4];
            #pragma unroll
            for (int i = 0; i < 4; ++i) {
                float lo = b[cur][2 * i], hi = b[cur][2 * i + 1];
                pacc = fmaf(lo, lo, pacc); pacc = fmaf(hi, hi, pacc);
                w[i] = (unsigned)f2bf(lo) | ((unsigned)f2bf(hi) << 16);
            }
            *(uint4*)&Bs[cur][pm][pk * 8] = make_uint4(w[0], w[1], w[2], w[3]);
        }

        __syncthreads();   // LDS[cur] ready (1 barrier/step dbuf, race-free)

        // ---- prefetch next step AFTER the barrier: in flight during MFMA,
        //      waited on only at next step's staging use.
        if (step < 7) {
            const float* pax = ax + (step + 1) * 64;
            a0[nxt] = *(const float4*)pax;
            a1[nxt] = *(const float4*)(pax + 4);
            const float* pbp = bp + (step + 1) * 64 * NM;
            #pragma unroll
            for (int j = 0; j < 8; ++j) b[nxt][j] = pbp[j * NM];
        }

        #pragma unroll
        for (int s = 0; s < 2; ++s) {
            const int kk = s * 32 + fq * 8;
            short8 af = *(const short8*)&As[cur][wn * 16 + fr][kk];
            short8 bf = *(const short8*)&Bs[cur][wm * 16 + fr][kk];
            acc = __builtin_amdgcn_mfma_f32_16x16x32_bf16(af, bf, acc, 0, 0, 0);
        }
    }

    // ---- norm reductions
    #pragma unroll
    for (int off = 4; off > 0; off >>= 1) xacc += __shfl_down(xacc, off, 8);
    if (sk == 0) xx_s[sr] = xacc;
    pp_part[pk][pm] = pacc;
    __syncthreads();

    // ---- epilogue: C/D layout col=lane&15, row=(lane>>4)*4+reg  [m89/m91]
    const int col = wm * 16 + fr;
    float pv = 0.f;
    #pragma unroll
    for (int i = 0; i < 8; ++i) pv += pp_part[i][col];
    float* orow = out + (n0 + wn * 16) * NM + m0 + col;
    #pragma unroll
    for (int r = 0; r < 4; ++r) {
        const int rowl = fq * 4 + r;
        const float xv = xx_s[wn * 16 + rowl];
        orow[rowl * NM] = -0.5f * sqrtf(fmaxf(xv + pv - 2.f * acc[r], 0.f));
    }
}

extern "C" void kernel_launch(void* const* d_in, const int* in_sizes, int n_in,
                              void* d_out, int out_size, void* d_ws, size_t ws_size,
                              hipStream_t stream) {
    const float* x     = (const float*)d_in[0];   // (N, D) f32
    const float* proto = (const float*)d_in[1];   // (D, M) f32
    float* out = (float*)d_out;                   // (N, M) f32
    hipLaunchKernelGGL(fused_kernel, dim3(NN / 32, NM / 32), dim3(256), 0, stream,
                       x, proto, out);
}